// Round 8
// baseline (1744.569 us; speedup 1.0000x reference)
//
#include <hip/hip_runtime.h>
#include <math.h>

#define NUM_CODE 20000
#define EMBED_D  256
#define HID      128
#define CC       64
#define NBV      3200
#define NB       2          // bv-rows per block, software-pipelined

typedef __attribute__((ext_vector_type(8))) short bf16x8;
typedef __attribute__((ext_vector_type(4))) float f32x4;

__device__ __forceinline__ unsigned f2bf1(float f) {
    union { float f; unsigned u; } c; c.f = f;
    return (c.u + 0x7FFFu + ((c.u >> 16) & 1u)) >> 16;   // RNE
}
__device__ __forceinline__ unsigned pk2(float lo, float hi) {
    return f2bf1(lo) | (f2bf1(hi) << 16);
}
__device__ __forceinline__ float bflo(unsigned u) {
    union { unsigned u; float f; } c; c.u = u << 16; return c.f;
}
__device__ __forceinline__ float bfhi(unsigned u) {
    union { unsigned u; float f; } c; c.u = u & 0xFFFF0000u; return c.f;
}
__device__ __forceinline__ float tanh_fast(float x) {
    float t = __expf(2.0f * x);
    return 1.0f - 2.0f / (1.0f + t);
}

// ---------------------------------------------------------------------------
// Kernel 0: stream-convert table and W1 to bf16. Grid 5032 x 256.
// ---------------------------------------------------------------------------
__global__ __launch_bounds__(256) void cvt_kernel(
    const float* __restrict__ table, const float* __restrict__ W1,
    unsigned short* __restrict__ tbl_bf, unsigned short* __restrict__ W1b)
{
    int b = blockIdx.x;
    if (b < 5000) {
        int f = b * 256 + threadIdx.x;
        float4 v = ((const float4*)table)[f];
        uint2 o; o.x = pk2(v.x, v.y); o.y = pk2(v.z, v.w);
        ((uint2*)tbl_bf)[f] = o;
    } else {
        int f = (b - 5000) * 256 + threadIdx.x;
        float4 v = ((const float4*)W1)[f];
        uint2 o; o.x = pk2(v.x, v.y); o.y = pk2(v.z, v.w);
        ((uint2*)W1b)[f] = o;
    }
}

// ---------------------------------------------------------------------------
// Kernel 1: fused, NB=2 bv-rows per block, pipelined gathers, mask-skip.
// elen = len ? len : 64 (len==0 -> reference softmax is uniform over all 64).
// Work for code tiles >= ceil(elen/16) is skipped entirely (uniform branch).
// Stale-LDS rows only ever produce scores for c >= len, which the softmax
// select maps to -1e9 before any NaN can propagate; PV touches c < elen only.
// ---------------------------------------------------------------------------
__global__ __launch_bounds__(256, 4) void fused_kernel(
    const int* __restrict__ codes, const int* __restrict__ lens,
    const uint4* __restrict__ t16, const unsigned short* __restrict__ W1b,
    const float* __restrict__ b1, const float* __restrict__ W2,
    float* __restrict__ out)
{
    __shared__ uint4 smem4[2112];            // 33792 B: emb, later red
    __shared__ int   code_s[2][CC];
    __shared__ float comb[4][68];
    __shared__ float attn_s[CC];

    unsigned short* emb = (unsigned short*)smem4;   // [64][264] bf16

    const int tid = threadIdx.x;
    const int g   = tid >> 5;     // gather/PV group 0..7
    const int l   = tid & 31;     // 16B chunk within row
    const int l6  = tid & 63;
    const int w   = tid >> 6;     // wave 0..3
    const int row = l6 & 15;
    const int kg  = l6 >> 4;
    const int bv0 = blockIdx.x * NB;

    if (tid < CC) code_s[0][tid] = codes[(size_t)bv0 * CC + tid];
    __syncthreads();

    uint4 v[8];
    {
        int len0 = lens[bv0];
        int el0  = len0 ? len0 : CC;
#pragma unroll
        for (int cc = 0; cc < 8; cc++)
            if (cc * 8 + g < el0)
                v[cc] = t16[(size_t)code_s[0][cc * 8 + g] * 32 + l];
    }

#pragma unroll
    for (int i = 0; i < NB; ++i) {
        const int bv  = bv0 + i;
        const int len = lens[bv];
        const int el  = len ? len : CC;
        const int nm  = (el + 15) >> 4;      // active 16-row tiles, 1..4

        // stage current row's embeddings (only live rows)
#pragma unroll
        for (int cc = 0; cc < 8; cc++)
            if (cc * 8 + g < el)
                *(uint4*)&emb[(cc * 8 + g) * 264 + l * 8] = v[cc];
        if (i + 1 < NB && tid < CC)
            code_s[(i + 1) & 1][tid] = codes[(size_t)(bv + 1) * CC + tid];
        __syncthreads();

        // prefetch next row's gathers (in flight under GEMM/softmax/PV)
        if (i + 1 < NB) {
            int len1 = lens[bv + 1];
            int el1  = len1 ? len1 : CC;
#pragma unroll
            for (int cc = 0; cc < 8; cc++)
                if (cc * 8 + g < el1)
                    v[cc] = t16[(size_t)code_s[(i + 1) & 1][cc * 8 + g] * 32 + l];
        }

        // j-split GEMM over active M-tiles only
        const unsigned short* wb0 = W1b + (size_t)((2 * w) * 16 + row) * EMBED_D;
        const unsigned short* wb1 = wb0 + 16 * EMBED_D;
        f32x4 acc[4][2];
#pragma unroll
        for (int m = 0; m < 4; m++) {
            acc[m][0] = (f32x4){0.f, 0.f, 0.f, 0.f};
            acc[m][1] = (f32x4){0.f, 0.f, 0.f, 0.f};
        }
#pragma unroll
        for (int s = 0; s < 8; s++) {
            bf16x8 bw0 = *(const bf16x8*)(wb0 + s * 32 + kg * 8);
            bf16x8 bw1 = *(const bf16x8*)(wb1 + s * 32 + kg * 8);
#pragma unroll
            for (int m = 0; m < 4; m++) {
                if (m < nm) {
                    bf16x8 af = *(const bf16x8*)&emb[(16 * m + row) * 264 + s * 32 + kg * 8];
                    acc[m][0] = __builtin_amdgcn_mfma_f32_16x16x32_bf16(af, bw0, acc[m][0], 0, 0, 0);
                    acc[m][1] = __builtin_amdgcn_mfma_f32_16x16x32_bf16(af, bw1, acc[m][1], 0, 0, 0);
                }
            }
        }

        // partial epilogue (active tiles only); b2 dropped: shift-invariant
        float w2v[2], b1v[2];
#pragma unroll
        for (int jj = 0; jj < 2; jj++) {
            int n = (2 * w + jj) * 16 + row;
            w2v[jj] = W2[n];
            b1v[jj] = b1[n];
        }
#pragma unroll
        for (int m = 0; m < 4; m++) {
            if (m < nm) {
#pragma unroll
                for (int r = 0; r < 4; r++) {
                    float part = w2v[0] * tanh_fast(acc[m][0][r] + b1v[0])
                               + w2v[1] * tanh_fast(acc[m][1][r] + b1v[1]);
#pragma unroll
                    for (int o = 1; o < 16; o <<= 1)
                        part += __shfl_xor(part, o, 16);
                    if (row == 0)
                        comb[w][16 * m + kg * 4 + r] = part;
                }
            }
        }
        __syncthreads();

        // masked softmax over 64 codes
        if (tid < CC) {
            float sc = comb[0][tid] + comb[1][tid] + comb[2][tid] + comb[3][tid];
            float val = (tid < len) ? sc : -1e9f;
            float mx = val;
#pragma unroll
            for (int o = 32; o >= 1; o >>= 1)
                mx = fmaxf(mx, __shfl_xor(mx, o, 64));
            float e = __expf(val - mx);
            float sum = e;
#pragma unroll
            for (int o = 32; o >= 1; o >>= 1)
                sum += __shfl_xor(sum, o, 64);
            attn_s[tid] = e / sum;
        }
        __syncthreads();

        // PV from LDS (live rows only; attn is exactly 0 for skipped rows)
        float a2[8] = {0.f, 0.f, 0.f, 0.f, 0.f, 0.f, 0.f, 0.f};
#pragma unroll
        for (int cc = 0; cc < 8; cc++) {
            int c = cc * 8 + g;
            if (c < el) {
                float a = attn_s[c];
                uint4 q = *(const uint4*)&emb[c * 264 + l * 8];
                unsigned u;
                u = q.x; a2[0] += a * bflo(u); a2[1] += a * bfhi(u);
                u = q.y; a2[2] += a * bflo(u); a2[3] += a * bfhi(u);
                u = q.z; a2[4] += a * bflo(u); a2[5] += a * bfhi(u);
                u = q.w; a2[6] += a * bflo(u); a2[7] += a * bfhi(u);
            }
        }
        __syncthreads();          // all emb reads done -> red may overwrite

        float* red = (float*)smem4;   // [8][256] f32, aliases emb
        *(float4*)&red[g * 256 + l * 8]     = make_float4(a2[0], a2[1], a2[2], a2[3]);
        *(float4*)&red[g * 256 + l * 8 + 4] = make_float4(a2[4], a2[5], a2[6], a2[7]);
        __syncthreads();

        if (tid < 64) {
            float4 o = make_float4(0.f, 0.f, 0.f, 0.f);
#pragma unroll
            for (int g2 = 0; g2 < 8; g2++) {
                float4 r = *(const float4*)&red[g2 * 256 + tid * 4];
                o.x += r.x; o.y += r.y; o.z += r.z; o.w += r.w;
            }
            ((float4*)out)[(size_t)bv * 64 + tid] = o;
        }
        __syncthreads();          // red reads done -> next stage may overwrite
    }
}

extern "C" void kernel_launch(void* const* d_in, const int* in_sizes, int n_in,
                              void* d_out, int out_size, void* d_ws, size_t ws_size,
                              hipStream_t stream) {
    const int*   codes = (const int*)d_in[0];   // [64,50,64]
    const int*   lens  = (const int*)d_in[1];   // [64,50]
    const float* table = (const float*)d_in[2]; // [20000,256]
    const float* W1 = (const float*)d_in[3];    // [128,256]
    const float* b1 = (const float*)d_in[4];    // [128]
    const float* W2 = (const float*)d_in[5];    // [1,128]
    // b2 (d_in[6]) unused: softmax is shift-invariant.
    float* out = (float*)d_out;                 // [64,50,256]

    // ws: tbl_bf (10.24 MB) | W1b (64 KB)
    unsigned short* tbl_bf = (unsigned short*)d_ws;
    unsigned short* W1b    = (unsigned short*)((char*)d_ws
                              + (size_t)NUM_CODE * EMBED_D * 2);

    cvt_kernel<<<5032, 256, 0, stream>>>(table, W1, tbl_bf, W1b);
    fused_kernel<<<NBV / NB, 256, 0, stream>>>(codes, lens, (const uint4*)tbl_bf,
                                               W1b, b1, W2, out);
}